// Round 13
// baseline (1160.587 us; speedup 1.0000x reference)
//
#include <hip/hip_runtime.h>
#include <cstddef>

#define BB 4
#define SS 2304      // 48*48
#define FF 512
#define NH 8
#define DD 64
#define BSR (BB*SS)  // 9216 rows

typedef __attribute__((ext_vector_type(8))) short bf16x8;
typedef __attribute__((ext_vector_type(4))) float f32x4;
#define MFMA16(a,b,c) __builtin_amdgcn_mfma_f32_16x16x32_bf16((a),(b),(c),0,0,0)

__device__ __forceinline__ ushort f2bf_rne(float x) {
    uint u = __float_as_uint(x);
    uint r = u + 0x7fffu + ((u >> 16) & 1u);
    return (ushort)(r >> 16);
}
__device__ __forceinline__ float bfval(ushort h) {
    return __uint_as_float((uint)h << 16);
}
// packed bf16 convert: dst.lo16 = bf16(a), dst.hi16 = bf16(b)  (RNE)
__device__ __forceinline__ uint cvt_pk_bf16(float a, float b) {
    uint r;
    asm("v_cvt_pk_bf16_f32 %0, %1, %2" : "=v"(r) : "v"(a), "v"(b));
    return r;
}
__device__ __forceinline__ float lo16val(uint p) { return __uint_as_float(p << 16); }
__device__ __forceinline__ float hi16val(uint p) { return __uint_as_float(p & 0xffff0000u); }

// ---------------------------------------------------------------------------
// All 4 weight transpose+splits: W[k][n] -> Wt{hi,lo}[n][k] bf16 (z selects)
// ---------------------------------------------------------------------------
__global__ __launch_bounds__(256) void wtsplit_all(
    const float* __restrict__ w0, const float* __restrict__ w1,
    const float* __restrict__ w2, const float* __restrict__ w3,
    ushort* __restrict__ whi_all, ushort* __restrict__ wlo_all)
{
    __shared__ __align__(16) float tile[64][68];
    const int z = blockIdx.z;
    const float* w = (z == 0) ? w0 : (z == 1) ? w1 : (z == 2) ? w2 : w3;
    ushort* whi = whi_all + (size_t)z * FF * FF;
    ushort* wlo = wlo_all + (size_t)z * FF * FF;

    const int t  = threadIdx.x;
    const int kt = blockIdx.x;
    const int nt = blockIdx.y;
    {
        const int r  = t >> 2;
        const int cg = (t & 3) * 16;
        const float* src = w + (size_t)(kt * 64 + r) * FF + nt * 64 + cg;
        #pragma unroll
        for (int j = 0; j < 4; ++j)
            *(float4*)&tile[r][cg + 4 * j] = *(const float4*)(src + 4 * j);
    }
    __syncthreads();
    {
        const int n  = t >> 2;
        const int kg = (t & 3) * 16;
        uint H[8], L[8];
        #pragma unroll
        for (int j = 0; j < 8; ++j) {
            float x0 = tile[kg + 2 * j][n];
            float x1 = tile[kg + 2 * j + 1][n];
            uint hp = cvt_pk_bf16(x0, x1);
            H[j] = hp;
            L[j] = cvt_pk_bf16(x0 - lo16val(hp), x1 - hi16val(hp));
        }
        size_t off = (size_t)(nt * 64 + n) * FF + kt * 64 + kg;
        *(uint4*)(whi + off)     = make_uint4(H[0], H[1], H[2], H[3]);
        *(uint4*)(whi + off + 8) = make_uint4(H[4], H[5], H[6], H[7]);
        *(uint4*)(wlo + off)     = make_uint4(L[0], L[1], L[2], L[3]);
        *(uint4*)(wlo + off + 8) = make_uint4(L[4], L[5], L[6], L[7]);
    }
}

// ---------------------------------------------------------------------------
// Fused QKV projection, tile 64x128: z=0 q (3-term acc, hi-only out),
// z=1 k (3-term, hi/lo out), z=2 v (2-term, bf16-transposed [bh][d][s]).
// ---------------------------------------------------------------------------
__global__ __launch_bounds__(256) void proj_qkv(
    const float* __restrict__ q_in, const float* __restrict__ k_in,
    const float* __restrict__ v_in, const ushort* __restrict__ whi_all,
    const ushort* __restrict__ wlo_all, const float* __restrict__ bq,
    const float* __restrict__ bk, const float* __restrict__ bv,
    ushort* __restrict__ qhi,
    ushort* __restrict__ khi, ushort* __restrict__ klo,
    ushort* __restrict__ vthi)
{
    __shared__ __align__(16) ushort TL[9216];   // 18,432 B

    const int z = blockIdx.z;
    const float* X = (z == 0) ? q_in : (z == 1) ? k_in : v_in;
    const ushort* wth = whi_all + (size_t)z * FF * FF;
    const ushort* wtl = wlo_all + (size_t)z * FF * FF;
    const float* bias = (z == 0) ? bq : (z == 1) ? bk : bv;

    const int t  = threadIdx.x, w = t >> 6, l = t & 63;
    const int ar = l & 15, kg = (l >> 4) * 8;
    const int i0 = blockIdx.x * 64, j0 = blockIdx.y * 128;
    const int arow = i0 + w * 16 + ar;

    f32x4 acc[8];
    #pragma unroll
    for (int nt = 0; nt < 8; ++nt) acc[nt] = (f32x4){0.f, 0.f, 0.f, 0.f};

    for (int kk = 0; kk < FF; kk += 32) {
        const float* xr = X + (size_t)arow * FF + kk + kg;
        float4 f0 = *(const float4*)xr;
        float4 f1 = *(const float4*)(xr + 4);
        union { uint u[4]; bf16x8 v; } ah, al;
        ah.u[0] = cvt_pk_bf16(f0.x, f0.y);
        ah.u[1] = cvt_pk_bf16(f0.z, f0.w);
        ah.u[2] = cvt_pk_bf16(f1.x, f1.y);
        ah.u[3] = cvt_pk_bf16(f1.z, f1.w);
        if (z < 2) {
            al.u[0] = cvt_pk_bf16(f0.x - lo16val(ah.u[0]), f0.y - hi16val(ah.u[0]));
            al.u[1] = cvt_pk_bf16(f0.z - lo16val(ah.u[1]), f0.w - hi16val(ah.u[1]));
            al.u[2] = cvt_pk_bf16(f1.x - lo16val(ah.u[2]), f1.y - hi16val(ah.u[2]));
            al.u[3] = cvt_pk_bf16(f1.z - lo16val(ah.u[3]), f1.w - hi16val(ah.u[3]));
        }
        #pragma unroll
        for (int nt = 0; nt < 8; ++nt) {
            const size_t wo = (size_t)(j0 + nt * 16 + ar) * FF + kk + kg;
            bf16x8 bh = *(const bf16x8*)(wth + wo);
            bf16x8 bl = *(const bf16x8*)(wtl + wo);
            acc[nt] = MFMA16(ah.v, bh, acc[nt]);
            acc[nt] = MFMA16(ah.v, bl, acc[nt]);
            if (z < 2) acc[nt] = MFMA16(al.v, bh, acc[nt]);
        }
    }

    const int bidx = i0 / SS;
    const int s0b  = i0 - bidx * SS;
    const int rowl = w * 16 + ((l >> 4) << 2);

    if (z == 2) {
        #pragma unroll
        for (int nt = 0; nt < 8; ++nt) {
            const float bb = bias[j0 + nt * 16 + ar];
            #pragma unroll
            for (int r = 0; r < 4; ++r)
                TL[(nt * 16 + ar) * 72 + rowl + r] = f2bf_rne(acc[nt][r] + bb);
        }
        __syncthreads();
        const int d = t >> 1, hf = t & 1;
        const ushort* src = &TL[d * 72 + hf * 32];
        const size_t o = (((size_t)bidx * NH + ((j0 + d) >> 6)) * DD + (d & 63)) * SS
                       + s0b + hf * 32;
        *(uint4*)(vthi + o)      = *(const uint4*)(src);
        *(uint4*)(vthi + o + 8)  = *(const uint4*)(src + 8);
        *(uint4*)(vthi + o + 16) = *(const uint4*)(src + 16);
        *(uint4*)(vthi + o + 24) = *(const uint4*)(src + 24);
    } else if (z == 0) {
        const int rowf = t >> 2, qd = t & 3;
        const int colg = j0 + qd * 32;
        const size_t o = (((size_t)bidx * NH + (colg >> 6)) * SS + s0b + rowf) * DD
                       + (colg & 63);
        #pragma unroll
        for (int nt = 0; nt < 8; ++nt) {
            const float bb = bias[j0 + nt * 16 + ar];
            #pragma unroll
            for (int r = 0; r < 4; ++r)
                TL[(rowl + r) * 136 + nt * 16 + ar] = f2bf_rne(acc[nt][r] + bb);
        }
        __syncthreads();
        const ushort* src = &TL[rowf * 136 + qd * 32];
        *(uint4*)(qhi + o)      = *(const uint4*)(src);
        *(uint4*)(qhi + o + 8)  = *(const uint4*)(src + 8);
        *(uint4*)(qhi + o + 16) = *(const uint4*)(src + 16);
        *(uint4*)(qhi + o + 24) = *(const uint4*)(src + 24);
    } else {
        const int rowf = t >> 2, qd = t & 3;
        const int colg = j0 + qd * 32;
        const size_t o = (((size_t)bidx * NH + (colg >> 6)) * SS + s0b + rowf) * DD
                       + (colg & 63);
        #pragma unroll
        for (int nt = 0; nt < 8; ++nt) {
            const float bb = bias[j0 + nt * 16 + ar];
            #pragma unroll
            for (int r = 0; r < 4; ++r)
                TL[(rowl + r) * 136 + nt * 16 + ar] = f2bf_rne(acc[nt][r] + bb);
        }
        __syncthreads();
        {
            const ushort* src = &TL[rowf * 136 + qd * 32];
            *(uint4*)(khi + o)      = *(const uint4*)(src);
            *(uint4*)(khi + o + 8)  = *(const uint4*)(src + 8);
            *(uint4*)(khi + o + 16) = *(const uint4*)(src + 16);
            *(uint4*)(khi + o + 24) = *(const uint4*)(src + 24);
        }
        __syncthreads();
        #pragma unroll
        for (int nt = 0; nt < 8; ++nt) {
            const float bb = bias[j0 + nt * 16 + ar];
            #pragma unroll
            for (int r = 0; r < 4; ++r) {
                const float val = acc[nt][r] + bb;
                const ushort hv = f2bf_rne(val);
                TL[(rowl + r) * 136 + nt * 16 + ar] = f2bf_rne(val - bfval(hv));
            }
        }
        __syncthreads();
        {
            const ushort* src = &TL[rowf * 136 + qd * 32];
            *(uint4*)(klo + o)      = *(const uint4*)(src);
            *(uint4*)(klo + o + 8)  = *(const uint4*)(src + 8);
            *(uint4*)(klo + o + 16) = *(const uint4*)(src + 16);
            *(uint4*)(klo + o + 24) = *(const uint4*)(src + 24);
        }
    }
}

// ---------------------------------------------------------------------------
// Output projection: out = ctx @ wo + b (2-term, f32 out [row][FF])
// ---------------------------------------------------------------------------
__global__ __launch_bounds__(256) void proj_out(
    const float* __restrict__ X, const ushort* __restrict__ wth,
    const ushort* __restrict__ wtl, const float* __restrict__ bias,
    float* __restrict__ outf)
{
    const int t  = threadIdx.x, w = t >> 6, l = t & 63;
    const int ar = l & 15, kg = (l >> 4) * 8;
    const int i0 = blockIdx.x * 64, j0 = blockIdx.y * 128;
    const int arow = i0 + w * 16 + ar;

    f32x4 acc[8];
    #pragma unroll
    for (int nt = 0; nt < 8; ++nt) acc[nt] = (f32x4){0.f, 0.f, 0.f, 0.f};

    for (int kk = 0; kk < FF; kk += 32) {
        const float* xr = X + (size_t)arow * FF + kk + kg;
        float4 f0 = *(const float4*)xr;
        float4 f1 = *(const float4*)(xr + 4);
        union { uint u[4]; bf16x8 v; } ah;
        ah.u[0] = cvt_pk_bf16(f0.x, f0.y);
        ah.u[1] = cvt_pk_bf16(f0.z, f0.w);
        ah.u[2] = cvt_pk_bf16(f1.x, f1.y);
        ah.u[3] = cvt_pk_bf16(f1.z, f1.w);
        #pragma unroll
        for (int nt = 0; nt < 8; ++nt) {
            const size_t wo = (size_t)(j0 + nt * 16 + ar) * FF + kk + kg;
            bf16x8 bh = *(const bf16x8*)(wth + wo);
            bf16x8 bl = *(const bf16x8*)(wtl + wo);
            acc[nt] = MFMA16(ah.v, bh, acc[nt]);
            acc[nt] = MFMA16(ah.v, bl, acc[nt]);
        }
    }

    #pragma unroll
    for (int nt = 0; nt < 8; ++nt) {
        const int col = j0 + nt * 16 + ar;
        const float bb = bias[col];
        #pragma unroll
        for (int r = 0; r < 4; ++r) {
            const int rowl = w * 16 + (l >> 4) * 4 + r;
            outf[(size_t)(i0 + rowl) * FF + col] = acc[nt][r] + bb;
        }
    }
}

// ---------------------------------------------------------------------------
// Fused attention: per (q-tile 64, bh), 512 thr. 40 KB LDS -> 4 blocks/CU.
// Pass 1: 1-term QK, K-hi dbuf across KH/KL regions, 1 barrier/tile.
// Pass 2: 2-term QK (KH/KL single-buf) -> p -> swizzled PT tile ->
//         NT attn stores + 1-term PV (VH single-buf). 2 barriers/tile,
//         reg-prefetch of next tile covers the staging.
// ---------------------------------------------------------------------------
__global__ __launch_bounds__(512, 8) void fattn_kernel(
    const ushort* __restrict__ qhi,
    const ushort* __restrict__ khi, const ushort* __restrict__ klo,
    const ushort* __restrict__ vthi,
    float* __restrict__ attn_out, float* __restrict__ ctx)
{
    __shared__ __align__(16) unsigned char smem[40960];
    ushort* KH = (ushort*)smem;           // 8 KB [64][64] swizzled
    ushort* KL = KH + 4096;               // 8 KB (pass-1: second K-hi buf)
    ushort* VH = KL + 4096;               // 8 KB [64 d][64 k] swizzled
    float*  PT = (float*)(VH + 4096);     // 8 waves x [16][32] swz = 16 KB
    float*  redS = PT;                    // pass-1 overlay [2][64]

    const int t = threadIdx.x, w = t >> 6, l = t & 63;
    const int ar = l & 15, kgi = l >> 4;
    const int kg = kgi * 8;
    const int qs = w & 3, kh = w >> 2;

    // XCD-chunked decode (grid 1152 = 8 XCDs x 144)
    const int xcd = blockIdx.x & 7;
    const int pos = blockIdx.x >> 3;
    const int bh  = xcd * 4 + (pos / 36);
    const int qt  = pos % 36;
    const int q0  = qt * 64;
    const int b   = bh >> 3, h = bh & 7;
    const size_t base = (size_t)bh * SS * DD;
    const float SC = 0.125f * 1.44269504f;

    // q fragments (hi only)
    const size_t qo = base + (size_t)(q0 + qs * 16 + ar) * DD + kg;
    const bf16x8 qh0 = *(const bf16x8*)(qhi + qo);
    const bf16x8 qh1 = *(const bf16x8*)(qhi + qo + 32);

    // staging addresses
    const int srow = t >> 3, sc8 = t & 7;
    const int sidx = srow * 64 + ((sc8 ^ (srow & 7)) << 3);
    const ushort* khsrc = khi + base + srow * 64 + sc8 * 8;
    const ushort* klsrc = klo + base + srow * 64 + sc8 * 8;
    const ushort* vhsrc = vthi + ((size_t)bh * DD + srow) * SS + sc8 * 8;

    // fragment read offsets (swizzled K/V LDS)
    const int sw  = ar & 7;
    const int i00 = kh * 2048 + ar * 64;
    const int i01 = i00 + 1024;
    const int s00 = (kgi ^ sw) << 3;
    const int s01 = ((4 | kgi) ^ sw) << 3;
    const int svw = ((kh * 4 + kgi) ^ sw) << 3;

    // ================= Pass 1: Z only (1-term, m=0), K-hi dbuf ============
    float s_[4] = {0.f, 0.f, 0.f, 0.f};
    {
        uint4 rk = *(const uint4*)khsrc;
        *(uint4*)&KH[sidx] = rk;
        __syncthreads();
        for (int kt = 0; kt < 36; ++kt) {
            if (kt < 35) rk = *(const uint4*)(khsrc + (size_t)(kt + 1) * 4096);
            const ushort* KC = (kt & 1) ? KL : KH;
            bf16x8 b00 = *(const bf16x8*)&KC[i00 + s00];
            bf16x8 b01 = *(const bf16x8*)&KC[i00 + s01];
            bf16x8 b10 = *(const bf16x8*)&KC[i01 + s00];
            bf16x8 b11 = *(const bf16x8*)&KC[i01 + s01];
            f32x4 a0 = {0.f,0.f,0.f,0.f}, a1 = {0.f,0.f,0.f,0.f};
            __builtin_amdgcn_s_setprio(1);
            a0 = MFMA16(qh0, b00, a0); a1 = MFMA16(qh0, b10, a1);
            a0 = MFMA16(qh1, b01, a0); a1 = MFMA16(qh1, b11, a1);
            __builtin_amdgcn_s_setprio(0);
            #pragma unroll
            for (int r = 0; r < 4; ++r)
                s_[r] += exp2f(a0[r] * SC) + exp2f(a1[r] * SC);
            if (kt < 35) {
                ushort* KN = (kt & 1) ? KH : KL;
                *(uint4*)&KN[sidx] = rk;
            }
            __syncthreads();
        }
    }
    #pragma unroll
    for (int off = 1; off <= 8; off <<= 1) {
        #pragma unroll
        for (int r = 0; r < 4; ++r) s_[r] += __shfl_xor(s_[r], off);
    }
    if (ar == 0) {
        #pragma unroll
        for (int r = 0; r < 4; ++r)
            redS[kh * 64 + qs * 16 + kgi * 4 + r] = s_[r];
    }
    __syncthreads();
    float linv[4];
    #pragma unroll
    for (int r = 0; r < 4; ++r) {
        const int idx = qs * 16 + kgi * 4 + r;
        linv[r] = -__log2f(redS[idx] + redS[64 + idx]);
    }
    __syncthreads();   // redS reads done before PT reuse

    // ================= Pass 2: emit + PV (single-buf, 2 barriers/tile) ====
    float* PTw = PT + w * 512;                    // [16][32] granule-XOR swz
    float* asto = attn_out + ((size_t)bh * SS + q0 + qs * 16 + (l >> 2)) * SS
                + kh * 32 + (l & 3) * 8;

    f32x4 acc[4];
    #pragma unroll
    for (int nt = 0; nt < 4; ++nt) acc[nt] = (f32x4){0.f, 0.f, 0.f, 0.f};

    {
        uint4 a = *(const uint4*)khsrc;
        uint4 bq = *(const uint4*)klsrc;
        uint4 c = *(const uint4*)vhsrc;
        *(uint4*)&KH[sidx] = a;
        *(uint4*)&KL[sidx] = bq;
        *(uint4*)&VH[sidx] = c;
    }
    __syncthreads();

    // PT swizzled addresses (precomputed)
    const int ptW0a = (((ar >> 2) ^ 0) << 2) + (ar & 3);        // col=ar granule base (row-dependent XOR added below)
    for (int kt = 0; kt < 36; ++kt) {
        uint4 rkh, rkl, rvh;
        if (kt < 35) {
            rkh = *(const uint4*)(khsrc + (size_t)(kt + 1) * 4096);
            rkl = *(const uint4*)(klsrc + (size_t)(kt + 1) * 4096);
            rvh = *(const uint4*)(vhsrc + (size_t)(kt + 1) * 64);
        }

        // ---- QK^T (2-term: qh*kh + qh*kl) ----
        bf16x8 bh00 = *(const bf16x8*)&KH[i00 + s00];
        bf16x8 bh01 = *(const bf16x8*)&KH[i00 + s01];
        bf16x8 bl00 = *(const bf16x8*)&KL[i00 + s00];
        bf16x8 bl01 = *(const bf16x8*)&KL[i00 + s01];
        bf16x8 bh10 = *(const bf16x8*)&KH[i01 + s00];
        bf16x8 bh11 = *(const bf16x8*)&KH[i01 + s01];
        bf16x8 bl10 = *(const bf16x8*)&KL[i01 + s00];
        bf16x8 bl11 = *(const bf16x8*)&KL[i01 + s01];
        f32x4 a0 = {0.f,0.f,0.f,0.f}, a1 = {0.f,0.f,0.f,0.f};
        __builtin_amdgcn_s_setprio(1);
        a0 = MFMA16(qh0, bh00, a0); a1 = MFMA16(qh0, bh10, a1);
        a0 = MFMA16(qh0, bl00, a0); a1 = MFMA16(qh0, bl10, a1);
        a0 = MFMA16(qh1, bh01, a0); a1 = MFMA16(qh1, bh11, a1);
        a0 = MFMA16(qh1, bl01, a0); a1 = MFMA16(qh1, bl11, a1);
        __builtin_amdgcn_s_setprio(0);

        // ---- p = exp2(fma(a,SC,-log2 Z)) -> swizzled PT tile ----
        #pragma unroll
        for (int r = 0; r < 4; ++r) {
            const int row = kgi * 4 + r;
            const int rx  = (row & 7) << 2;
            float p0 = exp2f(fmaf(a0[r], SC, linv[r]));
            float p1 = exp2f(fmaf(a1[r], SC, linv[r]));
            PTw[row * 32 + (ptW0a ^ rx)]        = p0;   // col = ar
            PTw[row * 32 + (ptW0a ^ rx ^ 16)]   = p1;   // col = 16+ar (g +4)
        }

        // ---- coalesced nontemporal attn store (transposed read) ----
        {
            const int row = l >> 2;
            const int rx  = (row & 7) << 2;
            const int g0  = ((l & 3) * 2) << 2;     // granule byte base *4 floats
            f32x4 sv0 = *(const f32x4*)&PTw[row * 32 + ((g0) ^ rx)];
            f32x4 sv1 = *(const f32x4*)&PTw[row * 32 + ((g0 + 4) ^ rx)];
            f32x4* dst = (f32x4*)(asto + (size_t)kt * 64);
            __builtin_nontemporal_store(sv0, dst);
            __builtin_nontemporal_store(sv1, dst + 1);
        }

        // ---- PV (1-term: p_hi*v_hi), cvt_pk pack ----
        {
            const int rx = (ar & 7) << 2;
            f32x4 pf0 = *(const f32x4*)&PTw[ar * 32 + ((kgi * 8) ^ rx)];
            f32x4 pf1 = *(const f32x4*)&PTw[ar * 32 + ((kgi * 8 + 4) ^ rx)];
            union { uint u[4]; bf16x8 v; } pah;
            pah.u[0] = cvt_pk_bf16(pf0[0], pf0[1]);
            pah.u[1] = cvt_pk_bf16(pf0[2], pf0[3]);
            pah.u[2] = cvt_pk_bf16(pf1[0], pf1[1]);
            pah.u[3] = cvt_pk_bf16(pf1[2], pf1[3]);
            __builtin_amdgcn_s_setprio(1);
            #pragma unroll
            for (int nt = 0; nt < 4; ++nt) {
                const int vfi = (nt * 16 + ar) * 64 + svw;
                bf16x8 vh = *(const bf16x8*)&VH[vfi];
                acc[nt] = MFMA16(pah.v, vh, acc[nt]);
            }
            __builtin_amdgcn_s_setprio(0);
        }

        __syncthreads();                 // all reads of tile kt done
        if (kt < 35) {
            *(uint4*)&KH[sidx] = rkh;
            *(uint4*)&KL[sidx] = rkl;
            *(uint4*)&VH[sidx] = rvh;
            __syncthreads();             // staged tile visible
        }
    }

    // ---- cross-wave ctx reduction (kh pairs) ----
    float* SCR = (float*)smem;           // [8][16][68] = 34,816 B
    #pragma unroll
    for (int nt = 0; nt < 4; ++nt) {
        #pragma unroll
        for (int r = 0; r < 4; ++r)
            SCR[w * 1088 + (kgi * 4 + r) * 68 + nt * 16 + ar] = acc[nt][r];
    }
    __syncthreads();
    {
        const int rrow = t >> 3;
        const int dg   = (t & 7) * 8;
        const int rqs  = rrow >> 4, rl = rrow & 15;
        const float* s0p = SCR + rqs * 1088 + rl * 68 + dg;
        const float* s1p = s0p + 4 * 1088;
        f32x4 o0, o1;
        #pragma unroll
        for (int j = 0; j < 4; ++j) o0[j] = s0p[j] + s1p[j];
        #pragma unroll
        for (int j = 0; j < 4; ++j) o1[j] = s0p[4 + j] + s1p[4 + j];
        float* cdst = ctx + ((size_t)b * SS + q0 + rrow) * FF + h * DD + dg;
        *(f32x4*)cdst = o0;
        *(f32x4*)(cdst + 4) = o1;
    }
}

extern "C" void kernel_launch(void* const* d_in, const int* in_sizes, int n_in,
                              void* d_out, int out_size, void* d_ws, size_t ws_size,
                              hipStream_t stream) {
    (void)in_sizes; (void)n_in; (void)out_size; (void)ws_size;
    const float* query = (const float*)d_in[0];
    const float* value = (const float*)d_in[1];
    const float* keys  = (const float*)d_in[2];
    const float* wq_w  = (const float*)d_in[3];
    const float* wq_b  = (const float*)d_in[4];
    const float* wk_w  = (const float*)d_in[5];
    const float* wk_b  = (const float*)d_in[6];
    const float* wv_w  = (const float*)d_in[7];
    const float* wv_b  = (const float*)d_in[8];
    const float* wo_w  = (const float*)d_in[9];
    const float* wo_b  = (const float*)d_in[10];

    float* out  = (float*)d_out;
    float* attn = out + (size_t)BB * SS * FF;

    const size_t NQ = (size_t)BB * NH * SS * DD;   // 4,718,592
    ushort* qhi    = (ushort*)d_ws;
    ushort* khi    = qhi + NQ;
    ushort* klo    = khi + NQ;
    ushort* vthi   = klo + NQ;
    float*  vstage = (float*)(vthi + NQ);          // ctx buffer
    ushort* wthi   = (ushort*)(vstage + NQ);       // 4 x FF*FF
    ushort* wtlo   = wthi + (size_t)4 * FF * FF;

    dim3 gwt(FF / 64, FF / 64, 4);
    dim3 gqkv(BSR / 64, FF / 128, 3);
    dim3 gproj(BSR / 64, FF / 128);

    wtsplit_all<<<gwt, 256, 0, stream>>>(wq_w, wk_w, wv_w, wo_w, wthi, wtlo);
    proj_qkv<<<gqkv, 256, 0, stream>>>(query, keys, value, wthi, wtlo,
                                       wq_b, wk_b, wv_b,
                                       qhi, khi, klo, vthi);

    fattn_kernel<<<36 * 32, 512, 0, stream>>>(qhi, khi, klo, vthi,
                                              attn, vstage);

    proj_out<<<gproj, 256, 0, stream>>>(vstage, wthi + (size_t)3 * FF * FF,
                                        wtlo + (size_t)3 * FF * FF, wo_b, out);
}

// Round 14
// 638.928 us; speedup vs baseline: 1.8165x; 1.8165x over previous
//
#include <hip/hip_runtime.h>
#include <cstddef>

#define BB 4
#define SS 2304      // 48*48
#define FF 512
#define NH 8
#define DD 64
#define BSR (BB*SS)  // 9216 rows

typedef __attribute__((ext_vector_type(8))) short bf16x8;
typedef __attribute__((ext_vector_type(4))) float f32x4;
#define MFMA16(a,b,c) __builtin_amdgcn_mfma_f32_16x16x32_bf16((a),(b),(c),0,0,0)

__device__ __forceinline__ ushort f2bf_rne(float x) {
    uint u = __float_as_uint(x);
    uint r = u + 0x7fffu + ((u >> 16) & 1u);
    return (ushort)(r >> 16);
}
__device__ __forceinline__ float bfval(ushort h) {
    return __uint_as_float((uint)h << 16);
}
// packed bf16 convert: dst.lo16 = bf16(a), dst.hi16 = bf16(b)  (RNE)
__device__ __forceinline__ uint cvt_pk_bf16(float a, float b) {
    uint r;
    asm("v_cvt_pk_bf16_f32 %0, %1, %2" : "=v"(r) : "v"(a), "v"(b));
    return r;
}
__device__ __forceinline__ float lo16val(uint p) { return __uint_as_float(p << 16); }
__device__ __forceinline__ float hi16val(uint p) { return __uint_as_float(p & 0xffff0000u); }

// ---------------------------------------------------------------------------
// All 4 weight transpose+splits: W[k][n] -> Wt{hi,lo}[n][k] bf16 (z selects)
// ---------------------------------------------------------------------------
__global__ __launch_bounds__(256) void wtsplit_all(
    const float* __restrict__ w0, const float* __restrict__ w1,
    const float* __restrict__ w2, const float* __restrict__ w3,
    ushort* __restrict__ whi_all, ushort* __restrict__ wlo_all)
{
    __shared__ __align__(16) float tile[64][68];
    const int z = blockIdx.z;
    const float* w = (z == 0) ? w0 : (z == 1) ? w1 : (z == 2) ? w2 : w3;
    ushort* whi = whi_all + (size_t)z * FF * FF;
    ushort* wlo = wlo_all + (size_t)z * FF * FF;

    const int t  = threadIdx.x;
    const int kt = blockIdx.x;
    const int nt = blockIdx.y;
    {
        const int r  = t >> 2;
        const int cg = (t & 3) * 16;
        const float* src = w + (size_t)(kt * 64 + r) * FF + nt * 64 + cg;
        #pragma unroll
        for (int j = 0; j < 4; ++j)
            *(float4*)&tile[r][cg + 4 * j] = *(const float4*)(src + 4 * j);
    }
    __syncthreads();
    {
        const int n  = t >> 2;
        const int kg = (t & 3) * 16;
        uint H[8], L[8];
        #pragma unroll
        for (int j = 0; j < 8; ++j) {
            float x0 = tile[kg + 2 * j][n];
            float x1 = tile[kg + 2 * j + 1][n];
            uint hp = cvt_pk_bf16(x0, x1);
            H[j] = hp;
            L[j] = cvt_pk_bf16(x0 - lo16val(hp), x1 - hi16val(hp));
        }
        size_t off = (size_t)(nt * 64 + n) * FF + kt * 64 + kg;
        *(uint4*)(whi + off)     = make_uint4(H[0], H[1], H[2], H[3]);
        *(uint4*)(whi + off + 8) = make_uint4(H[4], H[5], H[6], H[7]);
        *(uint4*)(wlo + off)     = make_uint4(L[0], L[1], L[2], L[3]);
        *(uint4*)(wlo + off + 8) = make_uint4(L[4], L[5], L[6], L[7]);
    }
}

// ---------------------------------------------------------------------------
// Fused QKV projection, tile 64x128: z=0 q (3-term acc, hi-only out),
// z=1 k (3-term, hi/lo out), z=2 v (2-term, bf16-transposed [bh][d][s]).
// ---------------------------------------------------------------------------
__global__ __launch_bounds__(256) void proj_qkv(
    const float* __restrict__ q_in, const float* __restrict__ k_in,
    const float* __restrict__ v_in, const ushort* __restrict__ whi_all,
    const ushort* __restrict__ wlo_all, const float* __restrict__ bq,
    const float* __restrict__ bk, const float* __restrict__ bv,
    ushort* __restrict__ qhi,
    ushort* __restrict__ khi, ushort* __restrict__ klo,
    ushort* __restrict__ vthi)
{
    __shared__ __align__(16) ushort TL[9216];   // 18,432 B

    const int z = blockIdx.z;
    const float* X = (z == 0) ? q_in : (z == 1) ? k_in : v_in;
    const ushort* wth = whi_all + (size_t)z * FF * FF;
    const ushort* wtl = wlo_all + (size_t)z * FF * FF;
    const float* bias = (z == 0) ? bq : (z == 1) ? bk : bv;

    const int t  = threadIdx.x, w = t >> 6, l = t & 63;
    const int ar = l & 15, kg = (l >> 4) * 8;
    const int i0 = blockIdx.x * 64, j0 = blockIdx.y * 128;
    const int arow = i0 + w * 16 + ar;

    f32x4 acc[8];
    #pragma unroll
    for (int nt = 0; nt < 8; ++nt) acc[nt] = (f32x4){0.f, 0.f, 0.f, 0.f};

    for (int kk = 0; kk < FF; kk += 32) {
        const float* xr = X + (size_t)arow * FF + kk + kg;
        float4 f0 = *(const float4*)xr;
        float4 f1 = *(const float4*)(xr + 4);
        union { uint u[4]; bf16x8 v; } ah, al;
        ah.u[0] = cvt_pk_bf16(f0.x, f0.y);
        ah.u[1] = cvt_pk_bf16(f0.z, f0.w);
        ah.u[2] = cvt_pk_bf16(f1.x, f1.y);
        ah.u[3] = cvt_pk_bf16(f1.z, f1.w);
        if (z < 2) {
            al.u[0] = cvt_pk_bf16(f0.x - lo16val(ah.u[0]), f0.y - hi16val(ah.u[0]));
            al.u[1] = cvt_pk_bf16(f0.z - lo16val(ah.u[1]), f0.w - hi16val(ah.u[1]));
            al.u[2] = cvt_pk_bf16(f1.x - lo16val(ah.u[2]), f1.y - hi16val(ah.u[2]));
            al.u[3] = cvt_pk_bf16(f1.z - lo16val(ah.u[3]), f1.w - hi16val(ah.u[3]));
        }
        #pragma unroll
        for (int nt = 0; nt < 8; ++nt) {
            const size_t wo = (size_t)(j0 + nt * 16 + ar) * FF + kk + kg;
            bf16x8 bh = *(const bf16x8*)(wth + wo);
            bf16x8 bl = *(const bf16x8*)(wtl + wo);
            acc[nt] = MFMA16(ah.v, bh, acc[nt]);
            acc[nt] = MFMA16(ah.v, bl, acc[nt]);
            if (z < 2) acc[nt] = MFMA16(al.v, bh, acc[nt]);
        }
    }

    const int bidx = i0 / SS;
    const int s0b  = i0 - bidx * SS;
    const int rowl = w * 16 + ((l >> 4) << 2);

    if (z == 2) {
        #pragma unroll
        for (int nt = 0; nt < 8; ++nt) {
            const float bb = bias[j0 + nt * 16 + ar];
            #pragma unroll
            for (int r = 0; r < 4; ++r)
                TL[(nt * 16 + ar) * 72 + rowl + r] = f2bf_rne(acc[nt][r] + bb);
        }
        __syncthreads();
        const int d = t >> 1, hf = t & 1;
        const ushort* src = &TL[d * 72 + hf * 32];
        const size_t o = (((size_t)bidx * NH + ((j0 + d) >> 6)) * DD + (d & 63)) * SS
                       + s0b + hf * 32;
        *(uint4*)(vthi + o)      = *(const uint4*)(src);
        *(uint4*)(vthi + o + 8)  = *(const uint4*)(src + 8);
        *(uint4*)(vthi + o + 16) = *(const uint4*)(src + 16);
        *(uint4*)(vthi + o + 24) = *(const uint4*)(src + 24);
    } else if (z == 0) {
        const int rowf = t >> 2, qd = t & 3;
        const int colg = j0 + qd * 32;
        const size_t o = (((size_t)bidx * NH + (colg >> 6)) * SS + s0b + rowf) * DD
                       + (colg & 63);
        #pragma unroll
        for (int nt = 0; nt < 8; ++nt) {
            const float bb = bias[j0 + nt * 16 + ar];
            #pragma unroll
            for (int r = 0; r < 4; ++r)
                TL[(rowl + r) * 136 + nt * 16 + ar] = f2bf_rne(acc[nt][r] + bb);
        }
        __syncthreads();
        const ushort* src = &TL[rowf * 136 + qd * 32];
        *(uint4*)(qhi + o)      = *(const uint4*)(src);
        *(uint4*)(qhi + o + 8)  = *(const uint4*)(src + 8);
        *(uint4*)(qhi + o + 16) = *(const uint4*)(src + 16);
        *(uint4*)(qhi + o + 24) = *(const uint4*)(src + 24);
    } else {
        const int rowf = t >> 2, qd = t & 3;
        const int colg = j0 + qd * 32;
        const size_t o = (((size_t)bidx * NH + (colg >> 6)) * SS + s0b + rowf) * DD
                       + (colg & 63);
        #pragma unroll
        for (int nt = 0; nt < 8; ++nt) {
            const float bb = bias[j0 + nt * 16 + ar];
            #pragma unroll
            for (int r = 0; r < 4; ++r)
                TL[(rowl + r) * 136 + nt * 16 + ar] = f2bf_rne(acc[nt][r] + bb);
        }
        __syncthreads();
        {
            const ushort* src = &TL[rowf * 136 + qd * 32];
            *(uint4*)(khi + o)      = *(const uint4*)(src);
            *(uint4*)(khi + o + 8)  = *(const uint4*)(src + 8);
            *(uint4*)(khi + o + 16) = *(const uint4*)(src + 16);
            *(uint4*)(khi + o + 24) = *(const uint4*)(src + 24);
        }
        __syncthreads();
        #pragma unroll
        for (int nt = 0; nt < 8; ++nt) {
            const float bb = bias[j0 + nt * 16 + ar];
            #pragma unroll
            for (int r = 0; r < 4; ++r) {
                const float val = acc[nt][r] + bb;
                const ushort hv = f2bf_rne(val);
                TL[(rowl + r) * 136 + nt * 16 + ar] = f2bf_rne(val - bfval(hv));
            }
        }
        __syncthreads();
        {
            const ushort* src = &TL[rowf * 136 + qd * 32];
            *(uint4*)(klo + o)      = *(const uint4*)(src);
            *(uint4*)(klo + o + 8)  = *(const uint4*)(src + 8);
            *(uint4*)(klo + o + 16) = *(const uint4*)(src + 16);
            *(uint4*)(klo + o + 24) = *(const uint4*)(src + 24);
        }
    }
}

// ---------------------------------------------------------------------------
// Output projection: out = ctx @ wo + b (2-term, f32 out [row][FF])
// ---------------------------------------------------------------------------
__global__ __launch_bounds__(256) void proj_out(
    const float* __restrict__ X, const ushort* __restrict__ wth,
    const ushort* __restrict__ wtl, const float* __restrict__ bias,
    float* __restrict__ outf)
{
    const int t  = threadIdx.x, w = t >> 6, l = t & 63;
    const int ar = l & 15, kg = (l >> 4) * 8;
    const int i0 = blockIdx.x * 64, j0 = blockIdx.y * 128;
    const int arow = i0 + w * 16 + ar;

    f32x4 acc[8];
    #pragma unroll
    for (int nt = 0; nt < 8; ++nt) acc[nt] = (f32x4){0.f, 0.f, 0.f, 0.f};

    for (int kk = 0; kk < FF; kk += 32) {
        const float* xr = X + (size_t)arow * FF + kk + kg;
        float4 f0 = *(const float4*)xr;
        float4 f1 = *(const float4*)(xr + 4);
        union { uint u[4]; bf16x8 v; } ah;
        ah.u[0] = cvt_pk_bf16(f0.x, f0.y);
        ah.u[1] = cvt_pk_bf16(f0.z, f0.w);
        ah.u[2] = cvt_pk_bf16(f1.x, f1.y);
        ah.u[3] = cvt_pk_bf16(f1.z, f1.w);
        #pragma unroll
        for (int nt = 0; nt < 8; ++nt) {
            const size_t wo = (size_t)(j0 + nt * 16 + ar) * FF + kk + kg;
            bf16x8 bh = *(const bf16x8*)(wth + wo);
            bf16x8 bl = *(const bf16x8*)(wtl + wo);
            acc[nt] = MFMA16(ah.v, bh, acc[nt]);
            acc[nt] = MFMA16(ah.v, bl, acc[nt]);
        }
    }

    #pragma unroll
    for (int nt = 0; nt < 8; ++nt) {
        const int col = j0 + nt * 16 + ar;
        const float bb = bias[col];
        #pragma unroll
        for (int r = 0; r < 4; ++r) {
            const int rowl = w * 16 + (l >> 4) * 4 + r;
            outf[(size_t)(i0 + rowl) * FF + col] = acc[nt][r] + bb;
        }
    }
}

// ---------------------------------------------------------------------------
// Fused attention: per (q-tile 64, bh), 512 thr. 40 KB LDS -> up to 4
// blocks/CU with natural (~60) VGPR allocation. launch_bounds(512,4) keeps
// the register allocator unconstrained enough to avoid spills (r13 lesson).
// Pass 1: 1-term QK, K-hi dbuf across KH/KL regions, 1 barrier/tile.
// Pass 2: 2-term QK (KH/KL single-buf) -> p -> swizzled PT tile ->
//         NT attn stores + 1-term PV (VH single-buf). 2 barriers/tile.
// ---------------------------------------------------------------------------
__global__ __launch_bounds__(512, 4) void fattn_kernel(
    const ushort* __restrict__ qhi,
    const ushort* __restrict__ khi, const ushort* __restrict__ klo,
    const ushort* __restrict__ vthi,
    float* __restrict__ attn_out, float* __restrict__ ctx)
{
    __shared__ __align__(16) unsigned char smem[40960];
    ushort* KH = (ushort*)smem;           // 8 KB [64][64] swizzled
    ushort* KL = KH + 4096;               // 8 KB (pass-1: second K-hi buf)
    ushort* VH = KL + 4096;               // 8 KB [64 d][64 k] swizzled
    float*  PT = (float*)(VH + 4096);     // 8 waves x [16][32] swz = 16 KB
    float*  redS = PT;                    // pass-1 overlay [2][64]

    const int t = threadIdx.x, w = t >> 6, l = t & 63;
    const int ar = l & 15, kgi = l >> 4;
    const int kg = kgi * 8;
    const int qs = w & 3, kh = w >> 2;

    // XCD-chunked decode (grid 1152 = 8 XCDs x 144)
    const int xcd = blockIdx.x & 7;
    const int pos = blockIdx.x >> 3;
    const int bh  = xcd * 4 + (pos / 36);
    const int qt  = pos % 36;
    const int q0  = qt * 64;
    const int b   = bh >> 3, h = bh & 7;
    const size_t base = (size_t)bh * SS * DD;
    const float SC = 0.125f * 1.44269504f;

    // q fragments (hi only)
    const size_t qo = base + (size_t)(q0 + qs * 16 + ar) * DD + kg;
    const bf16x8 qh0 = *(const bf16x8*)(qhi + qo);
    const bf16x8 qh1 = *(const bf16x8*)(qhi + qo + 32);

    // staging addresses
    const int srow = t >> 3, sc8 = t & 7;
    const int sidx = srow * 64 + ((sc8 ^ (srow & 7)) << 3);
    const ushort* khsrc = khi + base + srow * 64 + sc8 * 8;
    const ushort* klsrc = klo + base + srow * 64 + sc8 * 8;
    const ushort* vhsrc = vthi + ((size_t)bh * DD + srow) * SS + sc8 * 8;

    // fragment read offsets (swizzled K/V LDS)
    const int sw  = ar & 7;
    const int i00 = kh * 2048 + ar * 64;
    const int i01 = i00 + 1024;
    const int s00 = (kgi ^ sw) << 3;
    const int s01 = ((4 | kgi) ^ sw) << 3;
    const int svw = ((kh * 4 + kgi) ^ sw) << 3;

    // ================= Pass 1: Z only (1-term, m=0), K-hi dbuf ============
    float s_[4] = {0.f, 0.f, 0.f, 0.f};
    {
        uint4 rk = *(const uint4*)khsrc;
        *(uint4*)&KH[sidx] = rk;
        __syncthreads();
        for (int kt = 0; kt < 36; ++kt) {
            if (kt < 35) rk = *(const uint4*)(khsrc + (size_t)(kt + 1) * 4096);
            const ushort* KC = (kt & 1) ? KL : KH;
            bf16x8 b00 = *(const bf16x8*)&KC[i00 + s00];
            bf16x8 b01 = *(const bf16x8*)&KC[i00 + s01];
            bf16x8 b10 = *(const bf16x8*)&KC[i01 + s00];
            bf16x8 b11 = *(const bf16x8*)&KC[i01 + s01];
            f32x4 a0 = {0.f,0.f,0.f,0.f}, a1 = {0.f,0.f,0.f,0.f};
            __builtin_amdgcn_s_setprio(1);
            a0 = MFMA16(qh0, b00, a0); a1 = MFMA16(qh0, b10, a1);
            a0 = MFMA16(qh1, b01, a0); a1 = MFMA16(qh1, b11, a1);
            __builtin_amdgcn_s_setprio(0);
            #pragma unroll
            for (int r = 0; r < 4; ++r)
                s_[r] += exp2f(a0[r] * SC) + exp2f(a1[r] * SC);
            if (kt < 35) {
                ushort* KN = (kt & 1) ? KH : KL;
                *(uint4*)&KN[sidx] = rk;
            }
            __syncthreads();
        }
    }
    #pragma unroll
    for (int off = 1; off <= 8; off <<= 1) {
        #pragma unroll
        for (int r = 0; r < 4; ++r) s_[r] += __shfl_xor(s_[r], off);
    }
    if (ar == 0) {
        #pragma unroll
        for (int r = 0; r < 4; ++r)
            redS[kh * 64 + qs * 16 + kgi * 4 + r] = s_[r];
    }
    __syncthreads();
    float linv[4];
    #pragma unroll
    for (int r = 0; r < 4; ++r) {
        const int idx = qs * 16 + kgi * 4 + r;
        linv[r] = -__log2f(redS[idx] + redS[64 + idx]);
    }
    __syncthreads();   // redS reads done before PT reuse

    // ================= Pass 2: emit + PV (single-buf, 2 barriers/tile) ====
    float* PTw = PT + w * 512;                    // [16][32] granule-XOR swz
    float* asto = attn_out + ((size_t)bh * SS + q0 + qs * 16 + (l >> 2)) * SS
                + kh * 32 + (l & 3) * 8;

    f32x4 acc[4];
    #pragma unroll
    for (int nt = 0; nt < 4; ++nt) acc[nt] = (f32x4){0.f, 0.f, 0.f, 0.f};

    {
        uint4 a = *(const uint4*)khsrc;
        uint4 bq = *(const uint4*)klsrc;
        uint4 c = *(const uint4*)vhsrc;
        *(uint4*)&KH[sidx] = a;
        *(uint4*)&KL[sidx] = bq;
        *(uint4*)&VH[sidx] = c;
    }
    __syncthreads();

    const int ptW0a = (((ar >> 2) ^ 0) << 2) + (ar & 3);
    for (int kt = 0; kt < 36; ++kt) {
        uint4 rkh, rkl, rvh;
        if (kt < 35) {
            rkh = *(const uint4*)(khsrc + (size_t)(kt + 1) * 4096);
            rkl = *(const uint4*)(klsrc + (size_t)(kt + 1) * 4096);
            rvh = *(const uint4*)(vhsrc + (size_t)(kt + 1) * 64);
        }

        // ---- QK^T (2-term: qh*kh + qh*kl) ----
        bf16x8 bh00 = *(const bf16x8*)&KH[i00 + s00];
        bf16x8 bh01 = *(const bf16x8*)&KH[i00 + s01];
        bf16x8 bl00 = *(const bf16x8*)&KL[i00 + s00];
        bf16x8 bl01 = *(const bf16x8*)&KL[i00 + s01];
        bf16x8 bh10 = *(const bf16x8*)&KH[i01 + s00];
        bf16x8 bh11 = *(const bf16x8*)&KH[i01 + s01];
        bf16x8 bl10 = *(const bf16x8*)&KL[i01 + s00];
        bf16x8 bl11 = *(const bf16x8*)&KL[i01 + s01];
        f32x4 a0 = {0.f,0.f,0.f,0.f}, a1 = {0.f,0.f,0.f,0.f};
        __builtin_amdgcn_s_setprio(1);
        a0 = MFMA16(qh0, bh00, a0); a1 = MFMA16(qh0, bh10, a1);
        a0 = MFMA16(qh0, bl00, a0); a1 = MFMA16(qh0, bl10, a1);
        a0 = MFMA16(qh1, bh01, a0); a1 = MFMA16(qh1, bh11, a1);
        a0 = MFMA16(qh1, bl01, a0); a1 = MFMA16(qh1, bl11, a1);
        __builtin_amdgcn_s_setprio(0);

        // ---- p = exp2(fma(a,SC,-log2 Z)) -> swizzled PT tile ----
        #pragma unroll
        for (int r = 0; r < 4; ++r) {
            const int row = kgi * 4 + r;
            const int rx  = (row & 7) << 2;
            float p0 = exp2f(fmaf(a0[r], SC, linv[r]));
            float p1 = exp2f(fmaf(a1[r], SC, linv[r]));
            PTw[row * 32 + (ptW0a ^ rx)]        = p0;   // col = ar
            PTw[row * 32 + (ptW0a ^ rx ^ 16)]   = p1;   // col = 16+ar
        }

        // ---- coalesced nontemporal attn store (transposed read) ----
        {
            const int row = l >> 2;
            const int rx  = (row & 7) << 2;
            const int g0  = ((l & 3) * 2) << 2;
            f32x4 sv0 = *(const f32x4*)&PTw[row * 32 + ((g0) ^ rx)];
            f32x4 sv1 = *(const f32x4*)&PTw[row * 32 + ((g0 + 4) ^ rx)];
            f32x4* dst = (f32x4*)(asto + (size_t)kt * 64);
            __builtin_nontemporal_store(sv0, dst);
            __builtin_nontemporal_store(sv1, dst + 1);
        }

        // ---- PV (1-term: p_hi*v_hi), cvt_pk pack ----
        {
            const int rx = (ar & 7) << 2;
            f32x4 pf0 = *(const f32x4*)&PTw[ar * 32 + ((kgi * 8) ^ rx)];
            f32x4 pf1 = *(const f32x4*)&PTw[ar * 32 + ((kgi * 8 + 4) ^ rx)];
            union { uint u[4]; bf16x8 v; } pah;
            pah.u[0] = cvt_pk_bf16(pf0[0], pf0[1]);
            pah.u[1] = cvt_pk_bf16(pf0[2], pf0[3]);
            pah.u[2] = cvt_pk_bf16(pf1[0], pf1[1]);
            pah.u[3] = cvt_pk_bf16(pf1[2], pf1[3]);
            __builtin_amdgcn_s_setprio(1);
            #pragma unroll
            for (int nt = 0; nt < 4; ++nt) {
                const int vfi = (nt * 16 + ar) * 64 + svw;
                bf16x8 vh = *(const bf16x8*)&VH[vfi];
                acc[nt] = MFMA16(pah.v, vh, acc[nt]);
            }
            __builtin_amdgcn_s_setprio(0);
        }

        __syncthreads();                 // all reads of tile kt done
        if (kt < 35) {
            *(uint4*)&KH[sidx] = rkh;
            *(uint4*)&KL[sidx] = rkl;
            *(uint4*)&VH[sidx] = rvh;
            __syncthreads();             // staged tile visible
        }
    }

    // ---- cross-wave ctx reduction (kh pairs) ----
    float* SCR = (float*)smem;           // [8][16][68] = 34,816 B
    #pragma unroll
    for (int nt = 0; nt < 4; ++nt) {
        #pragma unroll
        for (int r = 0; r < 4; ++r)
            SCR[w * 1088 + (kgi * 4 + r) * 68 + nt * 16 + ar] = acc[nt][r];
    }
    __syncthreads();
    {
        const int rrow = t >> 3;
        const int dg   = (t & 7) * 8;
        const int rqs  = rrow >> 4, rl = rrow & 15;
        const float* s0p = SCR + rqs * 1088 + rl * 68 + dg;
        const float* s1p = s0p + 4 * 1088;
        f32x4 o0, o1;
        #pragma unroll
        for (int j = 0; j < 4; ++j) o0[j] = s0p[j] + s1p[j];
        #pragma unroll
        for (int j = 0; j < 4; ++j) o1[j] = s0p[4 + j] + s1p[4 + j];
        float* cdst = ctx + ((size_t)b * SS + q0 + rrow) * FF + h * DD + dg;
        *(f32x4*)cdst = o0;
        *(f32x4*)(cdst + 4) = o1;
    }
}

extern "C" void kernel_launch(void* const* d_in, const int* in_sizes, int n_in,
                              void* d_out, int out_size, void* d_ws, size_t ws_size,
                              hipStream_t stream) {
    (void)in_sizes; (void)n_in; (void)out_size; (void)ws_size;
    const float* query = (const float*)d_in[0];
    const float* value = (const float*)d_in[1];
    const float* keys  = (const float*)d_in[2];
    const float* wq_w  = (const float*)d_in[3];
    const float* wq_b  = (const float*)d_in[4];
    const float* wk_w  = (const float*)d_in[5];
    const float* wk_b  = (const float*)d_in[6];
    const float* wv_w  = (const float*)d_in[7];
    const float* wv_b  = (const float*)d_in[8];
    const float* wo_w  = (const float*)d_in[9];
    const float* wo_b  = (const float*)d_in[10];

    float* out  = (float*)d_out;
    float* attn = out + (size_t)BB * SS * FF;

    const size_t NQ = (size_t)BB * NH * SS * DD;   // 4,718,592
    ushort* qhi    = (ushort*)d_ws;
    ushort* khi    = qhi + NQ;
    ushort* klo    = khi + NQ;
    ushort* vthi   = klo + NQ;
    float*  vstage = (float*)(vthi + NQ);          // ctx buffer
    ushort* wthi   = (ushort*)(vstage + NQ);       // 4 x FF*FF
    ushort* wtlo   = wthi + (size_t)4 * FF * FF;

    dim3 gwt(FF / 64, FF / 64, 4);
    dim3 gqkv(BSR / 64, FF / 128, 3);
    dim3 gproj(BSR / 64, FF / 128);

    wtsplit_all<<<gwt, 256, 0, stream>>>(wq_w, wk_w, wv_w, wo_w, wthi, wtlo);
    proj_qkv<<<gqkv, 256, 0, stream>>>(query, keys, value, wthi, wtlo,
                                       wq_b, wk_b, wv_b,
                                       qhi, khi, klo, vthi);

    fattn_kernel<<<36 * 32, 512, 0, stream>>>(qhi, khi, klo, vthi,
                                              attn, vstage);

    proj_out<<<gproj, 256, 0, stream>>>(vstage, wthi + (size_t)3 * FF * FF,
                                        wtlo + (size_t)3 * FF * FF, wo_b, out);
}

// Round 15
// 603.778 us; speedup vs baseline: 1.9222x; 1.0582x over previous
//
#include <hip/hip_runtime.h>
#include <cstddef>

#define BB 4
#define SS 2304      // 48*48
#define FF 512
#define NH 8
#define DD 64
#define BSR (BB*SS)  // 9216 rows

typedef __attribute__((ext_vector_type(8))) short bf16x8;
typedef __attribute__((ext_vector_type(4))) float f32x4;
#define MFMA16(a,b,c) __builtin_amdgcn_mfma_f32_16x16x32_bf16((a),(b),(c),0,0,0)

__device__ __forceinline__ ushort f2bf_rne(float x) {
    uint u = __float_as_uint(x);
    uint r = u + 0x7fffu + ((u >> 16) & 1u);
    return (ushort)(r >> 16);
}
__device__ __forceinline__ float bfval(ushort h) {
    return __uint_as_float((uint)h << 16);
}
// packed bf16 convert: dst.lo16 = bf16(a), dst.hi16 = bf16(b)  (RNE)
__device__ __forceinline__ uint cvt_pk_bf16(float a, float b) {
    uint r;
    asm("v_cvt_pk_bf16_f32 %0, %1, %2" : "=v"(r) : "v"(a), "v"(b));
    return r;
}
__device__ __forceinline__ float lo16val(uint p) { return __uint_as_float(p << 16); }
__device__ __forceinline__ float hi16val(uint p) { return __uint_as_float(p & 0xffff0000u); }

// ---------------------------------------------------------------------------
// All 4 weight transpose+splits: W[k][n] -> Wt{hi,lo}[n][k] bf16 (z selects)
// ---------------------------------------------------------------------------
__global__ __launch_bounds__(256) void wtsplit_all(
    const float* __restrict__ w0, const float* __restrict__ w1,
    const float* __restrict__ w2, const float* __restrict__ w3,
    ushort* __restrict__ whi_all, ushort* __restrict__ wlo_all)
{
    __shared__ __align__(16) float tile[64][68];
    const int z = blockIdx.z;
    const float* w = (z == 0) ? w0 : (z == 1) ? w1 : (z == 2) ? w2 : w3;
    ushort* whi = whi_all + (size_t)z * FF * FF;
    ushort* wlo = wlo_all + (size_t)z * FF * FF;

    const int t  = threadIdx.x;
    const int kt = blockIdx.x;
    const int nt = blockIdx.y;
    {
        const int r  = t >> 2;
        const int cg = (t & 3) * 16;
        const float* src = w + (size_t)(kt * 64 + r) * FF + nt * 64 + cg;
        #pragma unroll
        for (int j = 0; j < 4; ++j)
            *(float4*)&tile[r][cg + 4 * j] = *(const float4*)(src + 4 * j);
    }
    __syncthreads();
    {
        const int n  = t >> 2;
        const int kg = (t & 3) * 16;
        uint H[8], L[8];
        #pragma unroll
        for (int j = 0; j < 8; ++j) {
            float x0 = tile[kg + 2 * j][n];
            float x1 = tile[kg + 2 * j + 1][n];
            uint hp = cvt_pk_bf16(x0, x1);
            H[j] = hp;
            L[j] = cvt_pk_bf16(x0 - lo16val(hp), x1 - hi16val(hp));
        }
        size_t off = (size_t)(nt * 64 + n) * FF + kt * 64 + kg;
        *(uint4*)(whi + off)     = make_uint4(H[0], H[1], H[2], H[3]);
        *(uint4*)(whi + off + 8) = make_uint4(H[4], H[5], H[6], H[7]);
        *(uint4*)(wlo + off)     = make_uint4(L[0], L[1], L[2], L[3]);
        *(uint4*)(wlo + off + 8) = make_uint4(L[4], L[5], L[6], L[7]);
    }
}

// ---------------------------------------------------------------------------
// Fused QKV projection, tile 64x128: z=0 q (3-term, hi/lo), z=1 k (3-term,
// hi/lo), z=2 v (2-term, bf16-transposed [bh][d][s] direct).
// ---------------------------------------------------------------------------
__global__ __launch_bounds__(256) void proj_qkv(
    const float* __restrict__ q_in, const float* __restrict__ k_in,
    const float* __restrict__ v_in, const ushort* __restrict__ whi_all,
    const ushort* __restrict__ wlo_all, const float* __restrict__ bq,
    const float* __restrict__ bk, const float* __restrict__ bv,
    ushort* __restrict__ qhi, ushort* __restrict__ qlo,
    ushort* __restrict__ khi, ushort* __restrict__ klo,
    ushort* __restrict__ vthi)
{
    __shared__ __align__(16) ushort TL[9216];   // 18,432 B

    const int z = blockIdx.z;
    const float* X = (z == 0) ? q_in : (z == 1) ? k_in : v_in;
    const ushort* wth = whi_all + (size_t)z * FF * FF;
    const ushort* wtl = wlo_all + (size_t)z * FF * FF;
    const float* bias = (z == 0) ? bq : (z == 1) ? bk : bv;

    const int t  = threadIdx.x, w = t >> 6, l = t & 63;
    const int ar = l & 15, kg = (l >> 4) * 8;
    const int i0 = blockIdx.x * 64, j0 = blockIdx.y * 128;
    const int arow = i0 + w * 16 + ar;

    f32x4 acc[8];
    #pragma unroll
    for (int nt = 0; nt < 8; ++nt) acc[nt] = (f32x4){0.f, 0.f, 0.f, 0.f};

    for (int kk = 0; kk < FF; kk += 32) {
        const float* xr = X + (size_t)arow * FF + kk + kg;
        float4 f0 = *(const float4*)xr;
        float4 f1 = *(const float4*)(xr + 4);
        union { uint u[4]; bf16x8 v; } ah, al;
        ah.u[0] = cvt_pk_bf16(f0.x, f0.y);
        ah.u[1] = cvt_pk_bf16(f0.z, f0.w);
        ah.u[2] = cvt_pk_bf16(f1.x, f1.y);
        ah.u[3] = cvt_pk_bf16(f1.z, f1.w);
        if (z < 2) {
            al.u[0] = cvt_pk_bf16(f0.x - lo16val(ah.u[0]), f0.y - hi16val(ah.u[0]));
            al.u[1] = cvt_pk_bf16(f0.z - lo16val(ah.u[1]), f0.w - hi16val(ah.u[1]));
            al.u[2] = cvt_pk_bf16(f1.x - lo16val(ah.u[2]), f1.y - hi16val(ah.u[2]));
            al.u[3] = cvt_pk_bf16(f1.z - lo16val(ah.u[3]), f1.w - hi16val(ah.u[3]));
        }
        #pragma unroll
        for (int nt = 0; nt < 8; ++nt) {
            const size_t wo = (size_t)(j0 + nt * 16 + ar) * FF + kk + kg;
            bf16x8 bh = *(const bf16x8*)(wth + wo);
            bf16x8 bl = *(const bf16x8*)(wtl + wo);
            acc[nt] = MFMA16(ah.v, bh, acc[nt]);
            acc[nt] = MFMA16(ah.v, bl, acc[nt]);
            if (z < 2) acc[nt] = MFMA16(al.v, bh, acc[nt]);
        }
    }

    const int bidx = i0 / SS;
    const int s0b  = i0 - bidx * SS;
    const int rowl = w * 16 + ((l >> 4) << 2);

    if (z == 2) {
        #pragma unroll
        for (int nt = 0; nt < 8; ++nt) {
            const float bb = bias[j0 + nt * 16 + ar];
            #pragma unroll
            for (int r = 0; r < 4; ++r)
                TL[(nt * 16 + ar) * 72 + rowl + r] = f2bf_rne(acc[nt][r] + bb);
        }
        __syncthreads();
        const int d = t >> 1, hf = t & 1;
        const ushort* src = &TL[d * 72 + hf * 32];
        const size_t o = (((size_t)bidx * NH + ((j0 + d) >> 6)) * DD + (d & 63)) * SS
                       + s0b + hf * 32;
        *(uint4*)(vthi + o)      = *(const uint4*)(src);
        *(uint4*)(vthi + o + 8)  = *(const uint4*)(src + 8);
        *(uint4*)(vthi + o + 16) = *(const uint4*)(src + 16);
        *(uint4*)(vthi + o + 24) = *(const uint4*)(src + 24);
    } else {
        ushort* ohi = (z == 0) ? qhi : khi;
        ushort* olo = (z == 0) ? qlo : klo;
        const int rowf = t >> 2, qd = t & 3;
        const int colg = j0 + qd * 32;
        const size_t o = (((size_t)bidx * NH + (colg >> 6)) * SS + s0b + rowf) * DD
                       + (colg & 63);
        #pragma unroll
        for (int nt = 0; nt < 8; ++nt) {
            const float bb = bias[j0 + nt * 16 + ar];
            #pragma unroll
            for (int r = 0; r < 4; ++r)
                TL[(rowl + r) * 136 + nt * 16 + ar] = f2bf_rne(acc[nt][r] + bb);
        }
        __syncthreads();
        {
            const ushort* src = &TL[rowf * 136 + qd * 32];
            *(uint4*)(ohi + o)      = *(const uint4*)(src);
            *(uint4*)(ohi + o + 8)  = *(const uint4*)(src + 8);
            *(uint4*)(ohi + o + 16) = *(const uint4*)(src + 16);
            *(uint4*)(ohi + o + 24) = *(const uint4*)(src + 24);
        }
        __syncthreads();
        #pragma unroll
        for (int nt = 0; nt < 8; ++nt) {
            const float bb = bias[j0 + nt * 16 + ar];
            #pragma unroll
            for (int r = 0; r < 4; ++r) {
                const float val = acc[nt][r] + bb;
                const ushort hv = f2bf_rne(val);
                TL[(rowl + r) * 136 + nt * 16 + ar] = f2bf_rne(val - bfval(hv));
            }
        }
        __syncthreads();
        {
            const ushort* src = &TL[rowf * 136 + qd * 32];
            *(uint4*)(olo + o)      = *(const uint4*)(src);
            *(uint4*)(olo + o + 8)  = *(const uint4*)(src + 8);
            *(uint4*)(olo + o + 16) = *(const uint4*)(src + 16);
            *(uint4*)(olo + o + 24) = *(const uint4*)(src + 24);
        }
    }
}

// ---------------------------------------------------------------------------
// Output projection: out = ctx @ wo + b (2-term, f32 out [row][FF])
// ---------------------------------------------------------------------------
__global__ __launch_bounds__(256) void proj_out(
    const float* __restrict__ X, const ushort* __restrict__ wth,
    const ushort* __restrict__ wtl, const float* __restrict__ bias,
    float* __restrict__ outf)
{
    const int t  = threadIdx.x, w = t >> 6, l = t & 63;
    const int ar = l & 15, kg = (l >> 4) * 8;
    const int i0 = blockIdx.x * 64, j0 = blockIdx.y * 128;
    const int arow = i0 + w * 16 + ar;

    f32x4 acc[8];
    #pragma unroll
    for (int nt = 0; nt < 8; ++nt) acc[nt] = (f32x4){0.f, 0.f, 0.f, 0.f};

    for (int kk = 0; kk < FF; kk += 32) {
        const float* xr = X + (size_t)arow * FF + kk + kg;
        float4 f0 = *(const float4*)xr;
        float4 f1 = *(const float4*)(xr + 4);
        union { uint u[4]; bf16x8 v; } ah;
        ah.u[0] = cvt_pk_bf16(f0.x, f0.y);
        ah.u[1] = cvt_pk_bf16(f0.z, f0.w);
        ah.u[2] = cvt_pk_bf16(f1.x, f1.y);
        ah.u[3] = cvt_pk_bf16(f1.z, f1.w);
        #pragma unroll
        for (int nt = 0; nt < 8; ++nt) {
            const size_t wo = (size_t)(j0 + nt * 16 + ar) * FF + kk + kg;
            bf16x8 bh = *(const bf16x8*)(wth + wo);
            bf16x8 bl = *(const bf16x8*)(wtl + wo);
            acc[nt] = MFMA16(ah.v, bh, acc[nt]);
            acc[nt] = MFMA16(ah.v, bl, acc[nt]);
        }
    }

    #pragma unroll
    for (int nt = 0; nt < 8; ++nt) {
        const int col = j0 + nt * 16 + ar;
        const float bb = bias[col];
        #pragma unroll
        for (int r = 0; r < 4; ++r) {
            const int rowl = w * 16 + (l >> 4) * 4 + r;
            outf[(size_t)(i0 + rowl) * FF + col] = acc[nt][r] + bb;
        }
    }
}

// ---------------------------------------------------------------------------
// Fused attention: per (q-tile 64, bh), 512 thr.
// Pass 1: 1-term QK (K-hi dbuf), exp-sum -> -log2(Z).
// Pass 2: 3-term QK (K hi/lo dbuf) -> p=exp2(fma) -> per-wave LDS tile ->
//         NT attn stores + 2-term PV (V-hi dbuf). 1 barrier/tile.
// ---------------------------------------------------------------------------
__global__ __launch_bounds__(512, 4) void fattn_kernel(
    const ushort* __restrict__ qhi, const ushort* __restrict__ qlo,
    const ushort* __restrict__ khi, const ushort* __restrict__ klo,
    const ushort* __restrict__ vthi,
    float* __restrict__ attn_out, float* __restrict__ ctx)
{
    __shared__ __align__(16) unsigned char smem[67584];
    ushort* KH0 = (ushort*)smem;          // [64][64] swizzled, dbuf
    ushort* KH1 = KH0 + 4096;
    ushort* KL0 = KH1 + 4096;
    ushort* KL1 = KL0 + 4096;
    ushort* VH0 = KL1 + 4096;             // [64 d][64 k] swizzled, dbuf
    ushort* VH1 = VH0 + 4096;
    float*  PT  = (float*)(VH1 + 4096);   // 8 waves x [16][36] f32
    float*  redS = PT;                    // pass-1 overlay [2][64]

    const int t = threadIdx.x, w = t >> 6, l = t & 63;
    const int ar = l & 15, kgi = l >> 4;
    const int kg = kgi * 8;
    const int qs = w & 3, kh = w >> 2;

    // XCD-chunked decode (grid 1152 = 8 XCDs x 144)
    const int xcd = blockIdx.x & 7;
    const int pos = blockIdx.x >> 3;
    const int bh  = xcd * 4 + (pos / 36);
    const int qt  = pos % 36;
    const int q0  = qt * 64;
    const int b   = bh >> 3, h = bh & 7;
    const size_t base = (size_t)bh * SS * DD;
    const float SC = 0.125f * 1.44269504f;

    // q fragments
    const size_t qo = base + (size_t)(q0 + qs * 16 + ar) * DD + kg;
    const bf16x8 qh0 = *(const bf16x8*)(qhi + qo);
    const bf16x8 qh1 = *(const bf16x8*)(qhi + qo + 32);
    const bf16x8 ql0 = *(const bf16x8*)(qlo + qo);
    const bf16x8 ql1 = *(const bf16x8*)(qlo + qo + 32);

    // staging addresses
    const int srow = t >> 3, sc8 = t & 7;
    const int sidx = srow * 64 + ((sc8 ^ (srow & 7)) << 3);
    const ushort* khsrc = khi + base + srow * 64 + sc8 * 8;
    const ushort* klsrc = klo + base + srow * 64 + sc8 * 8;
    const ushort* vhsrc = vthi + ((size_t)bh * DD + srow) * SS + sc8 * 8;

    // fragment read offsets (swizzled)
    const int sw  = ar & 7;
    const int i00 = kh * 2048 + ar * 64;
    const int i01 = i00 + 1024;
    const int s00 = (kgi ^ sw) << 3;
    const int s01 = ((4 | kgi) ^ sw) << 3;
    const int svw = ((kh * 4 + kgi) ^ sw) << 3;

    // ================= Pass 1: Z only (1-term, m=0) =================
    float s_[4] = {0.f, 0.f, 0.f, 0.f};
    {
        uint4 rk = *(const uint4*)khsrc;
        *(uint4*)&KH0[sidx] = rk;
        __syncthreads();
        for (int kt = 0; kt < 36; ++kt) {
            if (kt < 35) rk = *(const uint4*)(khsrc + (size_t)(kt + 1) * 4096);
            const ushort* KC = (kt & 1) ? KH1 : KH0;
            bf16x8 b00 = *(const bf16x8*)&KC[i00 + s00];
            bf16x8 b01 = *(const bf16x8*)&KC[i00 + s01];
            bf16x8 b10 = *(const bf16x8*)&KC[i01 + s00];
            bf16x8 b11 = *(const bf16x8*)&KC[i01 + s01];
            f32x4 a0 = {0.f,0.f,0.f,0.f}, a1 = {0.f,0.f,0.f,0.f};
            __builtin_amdgcn_s_setprio(1);
            a0 = MFMA16(qh0, b00, a0); a1 = MFMA16(qh0, b10, a1);
            a0 = MFMA16(qh1, b01, a0); a1 = MFMA16(qh1, b11, a1);
            __builtin_amdgcn_s_setprio(0);
            #pragma unroll
            for (int r = 0; r < 4; ++r)
                s_[r] += exp2f(a0[r] * SC) + exp2f(a1[r] * SC);
            if (kt < 35) {
                ushort* KN = (kt & 1) ? KH0 : KH1;
                *(uint4*)&KN[sidx] = rk;
            }
            __syncthreads();
        }
    }
    #pragma unroll
    for (int off = 1; off <= 8; off <<= 1) {
        #pragma unroll
        for (int r = 0; r < 4; ++r) s_[r] += __shfl_xor(s_[r], off);
    }
    if (ar == 0) {
        #pragma unroll
        for (int r = 0; r < 4; ++r)
            redS[kh * 64 + qs * 16 + kgi * 4 + r] = s_[r];
    }
    __syncthreads();
    float linv[4];
    #pragma unroll
    for (int r = 0; r < 4; ++r) {
        const int idx = qs * 16 + kgi * 4 + r;
        linv[r] = -__log2f(redS[idx] + redS[64 + idx]);
    }

    // ================= Pass 2: emit + PV (1 barrier/tile) =================
    float* PTw = PT + w * 576;                    // [16][36]
    float* asto = attn_out + ((size_t)bh * SS + q0 + qs * 16 + (l >> 2)) * SS
                + kh * 32 + (l & 3) * 8;

    f32x4 acc[4];
    #pragma unroll
    for (int nt = 0; nt < 4; ++nt) acc[nt] = (f32x4){0.f, 0.f, 0.f, 0.f};

    {
        uint4 a = *(const uint4*)khsrc;
        uint4 bq = *(const uint4*)klsrc;
        uint4 c = *(const uint4*)vhsrc;
        *(uint4*)&KH0[sidx] = a;
        *(uint4*)&KL0[sidx] = bq;
        *(uint4*)&VH0[sidx] = c;
    }
    __syncthreads();

    for (int kt = 0; kt < 36; ++kt) {
        uint4 rkh, rkl, rvh;
        if (kt < 35) {
            rkh = *(const uint4*)(khsrc + (size_t)(kt + 1) * 4096);
            rkl = *(const uint4*)(klsrc + (size_t)(kt + 1) * 4096);
            rvh = *(const uint4*)(vhsrc + (size_t)(kt + 1) * 64);
        }
        const ushort* KHc = (kt & 1) ? KH1 : KH0;
        const ushort* KLc = (kt & 1) ? KL1 : KL0;
        const ushort* VHc = (kt & 1) ? VH1 : VH0;

        // ---- QK^T (3-term) ----
        bf16x8 bh00 = *(const bf16x8*)&KHc[i00 + s00];
        bf16x8 bh01 = *(const bf16x8*)&KHc[i00 + s01];
        bf16x8 bl00 = *(const bf16x8*)&KLc[i00 + s00];
        bf16x8 bl01 = *(const bf16x8*)&KLc[i00 + s01];
        bf16x8 bh10 = *(const bf16x8*)&KHc[i01 + s00];
        bf16x8 bh11 = *(const bf16x8*)&KHc[i01 + s01];
        bf16x8 bl10 = *(const bf16x8*)&KLc[i01 + s00];
        bf16x8 bl11 = *(const bf16x8*)&KLc[i01 + s01];
        f32x4 a0 = {0.f,0.f,0.f,0.f}, a1 = {0.f,0.f,0.f,0.f};
        __builtin_amdgcn_s_setprio(1);
        a0 = MFMA16(qh0, bh00, a0); a1 = MFMA16(qh0, bh10, a1);
        a0 = MFMA16(qh0, bl00, a0); a1 = MFMA16(qh0, bl10, a1);
        a0 = MFMA16(ql0, bh00, a0); a1 = MFMA16(ql0, bh10, a1);
        a0 = MFMA16(qh1, bh01, a0); a1 = MFMA16(qh1, bh11, a1);
        a0 = MFMA16(qh1, bl01, a0); a1 = MFMA16(qh1, bl11, a1);
        a0 = MFMA16(ql1, bh01, a0); a1 = MFMA16(ql1, bh11, a1);
        __builtin_amdgcn_s_setprio(0);

        // ---- p = exp2(fma(a,SC,-log2 Z)) -> per-wave LDS tile ----
        #pragma unroll
        for (int r = 0; r < 4; ++r) {
            const int row = kgi * 4 + r;
            float p0 = exp2f(fmaf(a0[r], SC, linv[r]));
            float p1 = exp2f(fmaf(a1[r], SC, linv[r]));
            PTw[row * 36 + ar]      = p0;
            PTw[row * 36 + 16 + ar] = p1;
        }

        // ---- coalesced nontemporal attn store (transposed read) ----
        {
            const float* psr = PTw + (l >> 2) * 36 + (l & 3) * 8;
            f32x4 sv0 = *(const f32x4*)psr;
            f32x4 sv1 = *(const f32x4*)(psr + 4);
            f32x4* dst = (f32x4*)(asto + (size_t)kt * 64);
            __builtin_nontemporal_store(sv0, dst);
            __builtin_nontemporal_store(sv1, dst + 1);
        }

        // ---- PV (2-term: p_hi*v_hi + p_lo*v_hi), cvt_pk pack ----
        {
            const float* par = PTw + ar * 36 + kg;
            f32x4 pf0 = *(const f32x4*)par;
            f32x4 pf1 = *(const f32x4*)(par + 4);
            union { uint u[4]; bf16x8 v; } pah, pal;
            pah.u[0] = cvt_pk_bf16(pf0[0], pf0[1]);
            pah.u[1] = cvt_pk_bf16(pf0[2], pf0[3]);
            pah.u[2] = cvt_pk_bf16(pf1[0], pf1[1]);
            pah.u[3] = cvt_pk_bf16(pf1[2], pf1[3]);
            pal.u[0] = cvt_pk_bf16(pf0[0] - lo16val(pah.u[0]), pf0[1] - hi16val(pah.u[0]));
            pal.u[1] = cvt_pk_bf16(pf0[2] - lo16val(pah.u[1]), pf0[3] - hi16val(pah.u[1]));
            pal.u[2] = cvt_pk_bf16(pf1[0] - lo16val(pah.u[2]), pf1[1] - hi16val(pah.u[2]));
            pal.u[3] = cvt_pk_bf16(pf1[2] - lo16val(pah.u[3]), pf1[3] - hi16val(pah.u[3]));
            __builtin_amdgcn_s_setprio(1);
            #pragma unroll
            for (int nt = 0; nt < 4; ++nt) {
                const int vfi = (nt * 16 + ar) * 64 + svw;
                bf16x8 vh = *(const bf16x8*)&VHc[vfi];
                acc[nt] = MFMA16(pah.v, vh, acc[nt]);
                acc[nt] = MFMA16(pal.v, vh, acc[nt]);
            }
            __builtin_amdgcn_s_setprio(0);
        }

        // stage next tile into the other buffers
        if (kt < 35) {
            ushort* KHN = (kt & 1) ? KH0 : KH1;
            ushort* KLN = (kt & 1) ? KL0 : KL1;
            ushort* VHN = (kt & 1) ? VH0 : VH1;
            *(uint4*)&KHN[sidx] = rkh;
            *(uint4*)&KLN[sidx] = rkl;
            *(uint4*)&VHN[sidx] = rvh;
        }
        __syncthreads();
    }

    // ---- cross-wave ctx reduction (kh pairs) ----
    float* SCR = (float*)smem;           // [8][16][68]
    #pragma unroll
    for (int nt = 0; nt < 4; ++nt) {
        #pragma unroll
        for (int r = 0; r < 4; ++r)
            SCR[w * 1088 + (kgi * 4 + r) * 68 + nt * 16 + ar] = acc[nt][r];
    }
    __syncthreads();
    {
        const int rrow = t >> 3;
        const int dg   = (t & 7) * 8;
        const int rqs  = rrow >> 4, rl = rrow & 15;
        const float* s0p = SCR + rqs * 1088 + rl * 68 + dg;
        const float* s1p = s0p + 4 * 1088;
        f32x4 o0, o1;
        #pragma unroll
        for (int j = 0; j < 4; ++j) o0[j] = s0p[j] + s1p[j];
        #pragma unroll
        for (int j = 0; j < 4; ++j) o1[j] = s0p[4 + j] + s1p[4 + j];
        float* cdst = ctx + ((size_t)b * SS + q0 + rrow) * FF + h * DD + dg;
        *(f32x4*)cdst = o0;
        *(f32x4*)(cdst + 4) = o1;
    }
}

extern "C" void kernel_launch(void* const* d_in, const int* in_sizes, int n_in,
                              void* d_out, int out_size, void* d_ws, size_t ws_size,
                              hipStream_t stream) {
    (void)in_sizes; (void)n_in; (void)out_size; (void)ws_size;
    const float* query = (const float*)d_in[0];
    const float* value = (const float*)d_in[1];
    const float* keys  = (const float*)d_in[2];
    const float* wq_w  = (const float*)d_in[3];
    const float* wq_b  = (const float*)d_in[4];
    const float* wk_w  = (const float*)d_in[5];
    const float* wk_b  = (const float*)d_in[6];
    const float* wv_w  = (const float*)d_in[7];
    const float* wv_b  = (const float*)d_in[8];
    const float* wo_w  = (const float*)d_in[9];
    const float* wo_b  = (const float*)d_in[10];

    float* out  = (float*)d_out;
    float* attn = out + (size_t)BB * SS * FF;

    const size_t NQ = (size_t)BB * NH * SS * DD;   // 4,718,592
    ushort* qhi    = (ushort*)d_ws;
    ushort* qlo    = qhi + NQ;
    ushort* khi    = qlo + NQ;
    ushort* klo    = khi + NQ;
    ushort* vthi   = klo + NQ;
    float*  vstage = (float*)(vthi + NQ);          // ctx buffer
    ushort* wthi   = (ushort*)(vstage + NQ);       // 4 x FF*FF
    ushort* wtlo   = wthi + (size_t)4 * FF * FF;

    dim3 gwt(FF / 64, FF / 64, 4);
    dim3 gqkv(BSR / 64, FF / 128, 3);
    dim3 gproj(BSR / 64, FF / 128);

    wtsplit_all<<<gwt, 256, 0, stream>>>(wq_w, wk_w, wv_w, wo_w, wthi, wtlo);
    proj_qkv<<<gqkv, 256, 0, stream>>>(query, keys, value, wthi, wtlo,
                                       wq_b, wk_b, wv_b,
                                       qhi, qlo, khi, klo, vthi);

    fattn_kernel<<<36 * 32, 512, 0, stream>>>(qhi, qlo, khi, klo, vthi,
                                              attn, vstage);

    proj_out<<<gproj, 256, 0, stream>>>(vstage, wthi + (size_t)3 * FF * FF,
                                        wtlo + (size_t)3 * FF * FF, wo_b, out);
}